// Round 15
// baseline (893.358 us; speedup 1.0000x reference)
//
#include <hip/hip_runtime.h>
#include <math.h>

// GCN generator: B=8, N=F=128. One block/batch, 1024 threads (16 waves).
// Round 15: round 13 (541us) + prob dots via register-z partials:
//  - P2 epilogue: pivot-column lanes write z[:,pn] to s_zpiv[fo] (f32)
//  - P4 start: every thread folds its live z frags with s_zpiv -> pd
//    partials (32 fma + 4 shfl), z dies BEFORE mm_a (no MFMA-overlap
//    pressure - r14 spill lesson). 2-wave strided-dot tail deleted.
//  - P4c: wave 0 only: r=sum partials, sigmoid, out/patches, butterfly,
//    degrees, diag. s_prob eliminated. 3 barriers/step.

#define NN 128
#define SP 136

typedef _Float16 f16;
typedef _Float16 f16x8 __attribute__((ext_vector_type(8)));
typedef _Float16 f16x4 __attribute__((ext_vector_type(4)));
typedef _Float16 f16x2 __attribute__((ext_vector_type(2)));
typedef float f32x4 __attribute__((ext_vector_type(4)));

__device__ __forceinline__ f32x4 mm(f16x8 a, f16x8 b, f32x4 c) {
    return __builtin_amdgcn_mfma_f32_16x16x32_f16(a, b, c, 0, 0, 0);
}

__device__ __forceinline__ float rowdot8(f16x8 g, float acc) {
#if __has_builtin(__builtin_amdgcn_fdot2)
    const f16x2 one2 = {(f16)1.0f, (f16)1.0f};
    #pragma unroll
    for (int p = 0; p < 4; ++p) {
        f16x2 pr = {g[2*p], g[2*p+1]};
        acc = __builtin_amdgcn_fdot2(pr, one2, acc, false);
    }
#else
    #pragma unroll
    for (int e = 0; e < 8; ++e) acc += (float)g[e];
#endif
    return acc;
}

__global__ __launch_bounds__(1024)
void gcn_gen_kernel(const float* __restrict__ gx,
                    const float* __restrict__ gW,
                    const float* __restrict__ gb,
                    float* __restrict__ gout)
{
    extern __shared__ char lds_raw[];
    f16* X     = (f16*)lds_raw;              // [128][136] UNNORM z [n][f]
    f16* U     = X + NN*SP;                  // [128][136] u = x_hat.W, [fo][m]
    f16* Gb0   = U + NN*SP;                  // [128][136] M-hat' ping (diag+1)
    f16* Gb1   = Gb0 + NN*SP;                // [128][136] M-hat' pong
    f16* s_df16  = Gb1 + NN*SP;              // [128] d (f16)
    float* s_d    = (float*)(s_df16 + NN);   // [128] d (f32)
    float* s_diag = s_d + NN;                // [128] diag of carried C
    float* s_zpiv = s_diag + NN;             // [128] z[:,pn] by fo
    float* s_rows = s_zpiv + NN;             // [4][128] rowsum quarters (by wr)
    float* s_ssq  = s_rows + 4*NN;           // [4][128] ssq partials (by wr)
    float* s_pdt  = s_ssq + 4*NN;            // [4][128] zdot partials (by wr)

    const int b = blockIdx.x;
    const int t = threadIdx.x;
    const int lane = t & 63;
    const int w = t >> 6;
    const int wr = w >> 2, wc = w & 3;       // wave grid: wr=fo-block, wc=n-block
    const int lrow = lane & 15;
    const int lgrp = lane >> 4;
    const int r0 = wr*32 + lrow;             // A-row for mm_a / U-row for mm_b
    const int r1 = r0 + 16;
    const int n0 = wc*32 + lrow;             // Gc/X n-row for mm_b B-side
    const int n1 = n0 + 16;

    const float* xb = gx + (size_t)b*NN*NN;
    float* outb = gout + (size_t)b*NN*NN;

    // bias indexed by fo = wr*32 + rt*16 + lgrp*4 + q
    const float4 bv0 = *(const float4*)(gb + wr*32 + lgrp*4);
    const float4 bv1 = *(const float4*)(gb + wr*32 + 16 + lgrp*4);

    // ---- W -> registers as B-fragments for mm_a (k=fi, col=fo) ----
    f16x8 Wh[4][2];
    #pragma unroll
    for (int ks = 0; ks < 4; ++ks)
    #pragma unroll
    for (int ct = 0; ct < 2; ++ct) {
        const int col = wc*32 + ct*16 + lrow;
        #pragma unroll
        for (int r = 0; r < 8; ++r)
            Wh[ks][ct][r] = (f16)gW[(ks*32 + lgrp*8 + r)*NN + col];
    }

    // ---- init: X = f16(x), G0 = I with diag 2.0 (+I fold), out = eye ----
    #pragma unroll
    for (int q = 0; q < 16; ++q) {
        int idx = q*1024 + t;
        int r = idx >> 7, c = idx & 127;
        float e = (r == c) ? 1.f : 0.f;
        X[r*SP + c] = (f16)xb[idx];
        Gb0[r*SP + c] = (f16)(e * 2.f);      // M' = I + I
        outb[idx] = e;
    }
    if (t < NN) {
        s_d[t] = 0.70710678f;
        s_df16[t] = (f16)0.70710678f;
        s_diag[t] = 1.f;                     // diag(C_0) = 1
    }
    __syncthreads();

    // mm_a: u = (sv . X) . W -> U[fo][m]
    auto run_mma = [&](f16 sv0, f16 sv1) {
        f32x4 a2[2][2];
        #pragma unroll
        for (int rt = 0; rt < 2; ++rt)
        #pragma unroll
        for (int ct = 0; ct < 2; ++ct)
            a2[rt][ct] = (f32x4){0.f,0.f,0.f,0.f};
        #pragma unroll
        for (int ks = 0; ks < 4; ++ks) {
            const int ko = ks*32 + lgrp*8;
            f16x8 A0 = *(const f16x8*)(X + r0*SP + ko) * sv0;
            f16x8 A1 = *(const f16x8*)(X + r1*SP + ko) * sv1;
            a2[0][0] = mm(A0, Wh[ks][0], a2[0][0]);
            a2[0][1] = mm(A0, Wh[ks][1], a2[0][1]);
            a2[1][0] = mm(A1, Wh[ks][0], a2[1][0]);
            a2[1][1] = mm(A1, Wh[ks][1], a2[1][1]);
        }
        #pragma unroll
        for (int rt = 0; rt < 2; ++rt)
        #pragma unroll
        for (int ct = 0; ct < 2; ++ct) {
            f16x4 uv;
            #pragma unroll
            for (int q = 0; q < 4; ++q) uv[q] = (f16)a2[rt][ct][q];
            *(f16x4*)(U + (wc*32 + ct*16 + lrow)*SP + wr*32 + rt*16 + lgrp*4) = uv;
        }
    };
    run_mma((f16)1.0f, (f16)1.0f);
    __syncthreads();

    for (int i = 0; i < NN; ++i) {
        const int pn = i + 1;
        f16* Gc = (i & 1) ? Gb1 : Gb0;       // M-hat' (patched, diag = dgC+1)
        f16* Gn = (i & 1) ? Gb0 : Gb1;       // receives scaled carry

        // ========== P2: z^T = (U*dcv) . Gc-rows; carry; epilogue ==========
        f16x8 dcv[4];
        #pragma unroll
        for (int ks = 0; ks < 4; ++ks)
            dcv[ks] = *(const f16x8*)(s_df16 + ks*32 + lgrp*8);
        const f16 dn0h = s_df16[n0];
        const f16 dn1h = s_df16[n1];

        f32x4 acc[2][2];                     // [rt=fo][ct=n]
        #pragma unroll
        for (int rt = 0; rt < 2; ++rt)
        #pragma unroll
        for (int ct = 0; ct < 2; ++ct)
            acc[rt][ct] = (f32x4){0.f,0.f,0.f,0.f};
        float rs0 = 0.f, rs1 = 0.f;
        #pragma unroll
        for (int ks = 0; ks < 4; ++ks) {
            const int ko = ks*32 + lgrp*8;
            f16x8 A0 = *(const f16x8*)(U + r0*SP + ko) * dcv[ks];
            f16x8 A1 = *(const f16x8*)(U + r1*SP + ko) * dcv[ks];
            f16x8 B0 = *(const f16x8*)(Gc + n0*SP + ko);
            f16x8 B1 = *(const f16x8*)(Gc + n1*SP + ko);
            acc[0][0] = mm(A0, B0, acc[0][0]);
            acc[0][1] = mm(A0, B1, acc[0][1]);
            acc[1][0] = mm(A1, B0, acc[1][0]);
            acc[1][1] = mm(A1, B1, acc[1][1]);
            if (ks == wr) {                  // own (n in wc, k in wr) quarter
                f16x8 G0s = B0 * dcv[ks] * dn0h;
                f16x8 G1s = B1 * dcv[ks] * dn1h;
                *(f16x8*)(Gn + n0*SP + ko) = G0s;
                *(f16x8*)(Gn + n1*SP + ko) = G1s;
                rs0 = rowdot8(G0s, rs0);
                rs1 = rowdot8(G1s, rs1);
            }
        }
        rs0 += __shfl_xor(rs0, 16); rs0 += __shfl_xor(rs0, 32);
        rs1 += __shfl_xor(rs1, 16); rs1 += __shfl_xor(rs1, 32);
        if (lgrp == 0) {
            s_rows[wr*NN + n0] = rs0;
            s_rows[wr*NN + n1] = rs1;
        }

        // epilogue: z = dn * acc + bias(fo), relu; f16x4 -> X; ssq; zpiv
        const float dn[2] = { s_d[n0], s_d[n1] };
        float z[2][2][4];
        float ssc[2] = {0.f, 0.f};
        #pragma unroll
        for (int rt = 0; rt < 2; ++rt)
        #pragma unroll
        for (int ct = 0; ct < 2; ++ct) {
            f16x4 xv;
            #pragma unroll
            for (int q = 0; q < 4; ++q) {
                float bq = rt ? ((const float*)&bv1)[q] : ((const float*)&bv0)[q];
                float zv = fmaxf(fmaf(dn[ct], acc[rt][ct][q], bq), 0.f);
                z[rt][ct][q] = zv;
                ssc[ct] = fmaf(zv, zv, ssc[ct]);
                xv[q] = (f16)zv;
            }
            *(f16x4*)(X + (wc*32 + ct*16 + lrow)*SP + wr*32 + rt*16 + lgrp*4) = xv;
        }
        ssc[0] += __shfl_xor(ssc[0], 16); ssc[0] += __shfl_xor(ssc[0], 32);
        ssc[1] += __shfl_xor(ssc[1], 16); ssc[1] += __shfl_xor(ssc[1], 32);
        if (lgrp == 0) {
            s_ssq[wr*NN + n0] = ssc[0];
            s_ssq[wr*NN + n1] = ssc[1];
        }
        // pivot-column lanes stash z[:,pn] by fo (ternary ct select, no dyn idx)
        if (pn < NN && wc == (pn >> 5) && lrow == (pn & 15)) {
            const int ctp = (pn >> 4) & 1;
            float4 v0, v1;
            #pragma unroll
            for (int q = 0; q < 4; ++q) {
                ((float*)&v0)[q] = ctp ? z[0][1][q] : z[0][0][q];
                ((float*)&v1)[q] = ctp ? z[1][1][q] : z[1][0][q];
            }
            *(float4*)(s_zpiv + wr*32 + lgrp*4)      = v0;
            *(float4*)(s_zpiv + wr*32 + 16 + lgrp*4) = v1;
        }
        __syncthreads();

        // ========== P4: pd partials (z dies here), then mm_a ==========
        if (pn < NN) {
            {
                const float4 zp0 = *(const float4*)(s_zpiv + wr*32 + lgrp*4);
                const float4 zp1 = *(const float4*)(s_zpiv + wr*32 + 16 + lgrp*4);
                float pd0 = 0.f, pd1 = 0.f;
                #pragma unroll
                for (int q = 0; q < 4; ++q) {
                    float za = ((const float*)&zp0)[q];
                    float zb = ((const float*)&zp1)[q];
                    pd0 = fmaf(z[0][0][q], za, pd0);
                    pd0 = fmaf(z[1][0][q], zb, pd0);
                    pd1 = fmaf(z[0][1][q], za, pd1);
                    pd1 = fmaf(z[1][1][q], zb, pd1);
                }
                pd0 += __shfl_xor(pd0, 16); pd0 += __shfl_xor(pd0, 32);
                pd1 += __shfl_xor(pd1, 16); pd1 += __shfl_xor(pd1, 32);
                if (lgrp == 0) {
                    s_pdt[wr*NN + n0] = pd0;
                    s_pdt[wr*NN + n1] = pd1;
                }
            }
            f16 dvh[2];
            #pragma unroll
            for (int rt = 0; rt < 2; ++rt) {
                const int row = wr*32 + rt*16 + lrow;
                float sq = s_ssq[row] + s_ssq[NN+row] + s_ssq[2*NN+row] + s_ssq[3*NN+row];
                float dv = (i == 0) ? 1.f : 1.f/(sqrtf(sq) + 1e-8f);
                dvh[rt] = (f16)fminf(dv, 60000.f);
            }
            run_mma(dvh[0], dvh[1]);
        }
        __syncthreads();

        // ========== P4c (wave 0): probs, out/patches, degrees, diag ======
        if (pn < NN && w == 0) {
            float sqp = s_ssq[pn] + s_ssq[NN+pn] + s_ssq[2*NN+pn] + s_ssq[3*NN+pn];
            float dp = (i == 0) ? 1.f : 1.f/(sqrtf(sqp) + 1e-8f);
            float pv[2];
            float sp = 0.f;
            #pragma unroll
            for (int h = 0; h < 2; ++h) {
                const int tt = lane + h*64;
                float p = 0.f;
                if (tt < pn) {
                    float r = s_pdt[tt] + s_pdt[NN+tt] + s_pdt[2*NN+tt] + s_pdt[3*NN+tt];
                    float sqj = s_ssq[tt] + s_ssq[NN+tt] + s_ssq[2*NN+tt] + s_ssq[3*NN+tt];
                    float dj = (i == 0) ? 1.f : 1.f/(sqrtf(sqj) + 1e-8f);
                    p = 1.f/(1.f + expf(-0.5f*r*dj*dp));
                    f16 pf = (f16)p;
                    outb[pn*NN + tt] = p;
                    outb[tt*NN + pn] = p;
                    Gn[pn*SP + tt] = pf;          // patch row pn
                    Gn[tt*SP + pn] = pf;          // patch col pn
                    sp += p;
                }
                pv[h] = p;
            }
            #pragma unroll
            for (int m2 = 1; m2 < 64; m2 <<= 1) sp += __shfl_xor(sp, m2);
            #pragma unroll
            for (int h = 0; h < 2; ++h) {
                const int tt = lane + h*64;
                float rsC = s_rows[tt] + s_rows[NN+tt] + s_rows[2*NN+tt] + s_rows[3*NN+tt];
                float dgC = s_diag[tt];                   // diag(C_i)_t
                float rsM = (tt < pn) ? (rsC + pv[h])
                          : ((tt == pn) ? (sp + dgC) : rsC);
                float dnew = 1.f/sqrtf(rsM + 1.f + 1e-8f);
                s_d[tt] = dnew;
                s_df16[tt] = (f16)dnew;
                s_diag[tt] = dnew*dnew*(dgC + 1.f);       // diag(C_{i+1})
                Gn[tt*SP + tt] = (f16)(dgC + 1.f);        // stored diag = dgC+1
            }
        }
        __syncthreads();
    }
}

extern "C" void kernel_launch(void* const* d_in, const int* in_sizes, int n_in,
                              void* d_out, int out_size, void* d_ws, size_t ws_size,
                              hipStream_t stream) {
    const float* x  = (const float*)d_in[0];
    const float* W  = (const float*)d_in[1];
    const float* bb = (const float*)d_in[2];
    float* out = (float*)d_out;

    const size_t shmem = (size_t)(4*NN*SP + NN)*sizeof(f16)
                       + (size_t)(3*NN + 4*NN + 4*NN + 4*NN)*sizeof(float);
    hipFuncSetAttribute((const void*)gcn_gen_kernel,
                        hipFuncAttributeMaxDynamicSharedMemorySize, (int)shmem);
    gcn_gen_kernel<<<8, 1024, shmem, stream>>>(x, W, bb, out);
}

// Round 16
// 884.761 us; speedup vs baseline: 1.0097x; 1.0097x over previous
//
#include <hip/hip_runtime.h>
#include <math.h>

// GCN generator: B=8, N=F=128. One block/batch, 1024 threads (16 waves).
// Round 16: round 13 (541us) + prob dots WITHOUT register carry-over:
//  - P2 epilogue: pivot-column lanes stash z[:,pn] -> s_zpiv[fo] (f32),
//    while z is naturally live; z dies at end of P2 (r15 spill lesson).
//  - P4: each thread READS BACK its own z tile from X (f16, 4x b64,
//    conflict-free like the write), pd partial = sum z*zpiv, 2 shfl ->
//    s_pdt[wr]. Replaces the 2-wave 8-way-conflicted strided dot tail.
//  - P4c: wave 0 only: r=sum partials, sigmoid, out/patches, butterfly,
//    degrees, diag. s_prob deleted. 3 barriers/step.

#define NN 128
#define SP 136

typedef _Float16 f16;
typedef _Float16 f16x8 __attribute__((ext_vector_type(8)));
typedef _Float16 f16x4 __attribute__((ext_vector_type(4)));
typedef _Float16 f16x2 __attribute__((ext_vector_type(2)));
typedef float f32x4 __attribute__((ext_vector_type(4)));

__device__ __forceinline__ f32x4 mm(f16x8 a, f16x8 b, f32x4 c) {
    return __builtin_amdgcn_mfma_f32_16x16x32_f16(a, b, c, 0, 0, 0);
}

__device__ __forceinline__ float rowdot8(f16x8 g, float acc) {
#if __has_builtin(__builtin_amdgcn_fdot2)
    const f16x2 one2 = {(f16)1.0f, (f16)1.0f};
    #pragma unroll
    for (int p = 0; p < 4; ++p) {
        f16x2 pr = {g[2*p], g[2*p+1]};
        acc = __builtin_amdgcn_fdot2(pr, one2, acc, false);
    }
#else
    #pragma unroll
    for (int e = 0; e < 8; ++e) acc += (float)g[e];
#endif
    return acc;
}

__global__ __launch_bounds__(1024)
void gcn_gen_kernel(const float* __restrict__ gx,
                    const float* __restrict__ gW,
                    const float* __restrict__ gb,
                    float* __restrict__ gout)
{
    extern __shared__ char lds_raw[];
    f16* X     = (f16*)lds_raw;              // [128][136] UNNORM z [n][f]
    f16* U     = X + NN*SP;                  // [128][136] u = x_hat.W, [fo][m]
    f16* Gb0   = U + NN*SP;                  // [128][136] M-hat' ping (diag+1)
    f16* Gb1   = Gb0 + NN*SP;                // [128][136] M-hat' pong
    f16* s_df16  = Gb1 + NN*SP;              // [128] d (f16)
    float* s_d    = (float*)(s_df16 + NN);   // [128] d (f32)
    float* s_diag = s_d + NN;                // [128] diag of carried C
    float* s_zpiv = s_diag + NN;             // [128] z[:,pn] by fo (f32)
    float* s_rows = s_zpiv + NN;             // [4][128] rowsum quarters (by wr)
    float* s_ssq  = s_rows + 4*NN;           // [4][128] ssq partials (by wr)
    float* s_pdt  = s_ssq + 4*NN;            // [4][128] zdot partials (by wr)

    const int b = blockIdx.x;
    const int t = threadIdx.x;
    const int lane = t & 63;
    const int w = t >> 6;
    const int wr = w >> 2, wc = w & 3;       // wave grid: wr=fo-block, wc=n-block
    const int lrow = lane & 15;
    const int lgrp = lane >> 4;
    const int r0 = wr*32 + lrow;             // A-row for mm_a / U-row for mm_b
    const int r1 = r0 + 16;
    const int n0 = wc*32 + lrow;             // Gc/X n-row for mm_b B-side
    const int n1 = n0 + 16;

    const float* xb = gx + (size_t)b*NN*NN;
    float* outb = gout + (size_t)b*NN*NN;

    // bias indexed by fo = wr*32 + rt*16 + lgrp*4 + q
    const float4 bv0 = *(const float4*)(gb + wr*32 + lgrp*4);
    const float4 bv1 = *(const float4*)(gb + wr*32 + 16 + lgrp*4);

    // ---- W -> registers as B-fragments for mm_a (k=fi, col=fo) ----
    f16x8 Wh[4][2];
    #pragma unroll
    for (int ks = 0; ks < 4; ++ks)
    #pragma unroll
    for (int ct = 0; ct < 2; ++ct) {
        const int col = wc*32 + ct*16 + lrow;
        #pragma unroll
        for (int r = 0; r < 8; ++r)
            Wh[ks][ct][r] = (f16)gW[(ks*32 + lgrp*8 + r)*NN + col];
    }

    // ---- init: X = f16(x), G0 = I with diag 2.0 (+I fold), out = eye ----
    #pragma unroll
    for (int q = 0; q < 16; ++q) {
        int idx = q*1024 + t;
        int r = idx >> 7, c = idx & 127;
        float e = (r == c) ? 1.f : 0.f;
        X[r*SP + c] = (f16)xb[idx];
        Gb0[r*SP + c] = (f16)(e * 2.f);      // M' = I + I
        outb[idx] = e;
    }
    if (t < NN) {
        s_d[t] = 0.70710678f;
        s_df16[t] = (f16)0.70710678f;
        s_diag[t] = 1.f;                     // diag(C_0) = 1
    }
    __syncthreads();

    // mm_a: u = (sv . X) . W -> U[fo][m]
    auto run_mma = [&](f16 sv0, f16 sv1) {
        f32x4 a2[2][2];
        #pragma unroll
        for (int rt = 0; rt < 2; ++rt)
        #pragma unroll
        for (int ct = 0; ct < 2; ++ct)
            a2[rt][ct] = (f32x4){0.f,0.f,0.f,0.f};
        #pragma unroll
        for (int ks = 0; ks < 4; ++ks) {
            const int ko = ks*32 + lgrp*8;
            f16x8 A0 = *(const f16x8*)(X + r0*SP + ko) * sv0;
            f16x8 A1 = *(const f16x8*)(X + r1*SP + ko) * sv1;
            a2[0][0] = mm(A0, Wh[ks][0], a2[0][0]);
            a2[0][1] = mm(A0, Wh[ks][1], a2[0][1]);
            a2[1][0] = mm(A1, Wh[ks][0], a2[1][0]);
            a2[1][1] = mm(A1, Wh[ks][1], a2[1][1]);
        }
        #pragma unroll
        for (int rt = 0; rt < 2; ++rt)
        #pragma unroll
        for (int ct = 0; ct < 2; ++ct) {
            f16x4 uv;
            #pragma unroll
            for (int q = 0; q < 4; ++q) uv[q] = (f16)a2[rt][ct][q];
            *(f16x4*)(U + (wc*32 + ct*16 + lrow)*SP + wr*32 + rt*16 + lgrp*4) = uv;
        }
    };
    run_mma((f16)1.0f, (f16)1.0f);
    __syncthreads();

    for (int i = 0; i < NN; ++i) {
        const int pn = i + 1;
        f16* Gc = (i & 1) ? Gb1 : Gb0;       // M-hat' (patched, diag = dgC+1)
        f16* Gn = (i & 1) ? Gb0 : Gb1;       // receives scaled carry

        // ========== P2: z^T = (U*dcv) . Gc-rows; carry; epilogue ==========
        f16x8 dcv[4];
        #pragma unroll
        for (int ks = 0; ks < 4; ++ks)
            dcv[ks] = *(const f16x8*)(s_df16 + ks*32 + lgrp*8);
        const f16 dn0h = s_df16[n0];
        const f16 dn1h = s_df16[n1];

        f32x4 acc[2][2];                     // [rt=fo][ct=n]
        #pragma unroll
        for (int rt = 0; rt < 2; ++rt)
        #pragma unroll
        for (int ct = 0; ct < 2; ++ct)
            acc[rt][ct] = (f32x4){0.f,0.f,0.f,0.f};
        float rs0 = 0.f, rs1 = 0.f;
        #pragma unroll
        for (int ks = 0; ks < 4; ++ks) {
            const int ko = ks*32 + lgrp*8;
            f16x8 A0 = *(const f16x8*)(U + r0*SP + ko) * dcv[ks];
            f16x8 A1 = *(const f16x8*)(U + r1*SP + ko) * dcv[ks];
            f16x8 B0 = *(const f16x8*)(Gc + n0*SP + ko);
            f16x8 B1 = *(const f16x8*)(Gc + n1*SP + ko);
            acc[0][0] = mm(A0, B0, acc[0][0]);
            acc[0][1] = mm(A0, B1, acc[0][1]);
            acc[1][0] = mm(A1, B0, acc[1][0]);
            acc[1][1] = mm(A1, B1, acc[1][1]);
            if (ks == wr) {                  // own (n in wc, k in wr) quarter
                f16x8 G0s = B0 * dcv[ks] * dn0h;
                f16x8 G1s = B1 * dcv[ks] * dn1h;
                *(f16x8*)(Gn + n0*SP + ko) = G0s;
                *(f16x8*)(Gn + n1*SP + ko) = G1s;
                rs0 = rowdot8(G0s, rs0);
                rs1 = rowdot8(G1s, rs1);
            }
        }
        rs0 += __shfl_xor(rs0, 16); rs0 += __shfl_xor(rs0, 32);
        rs1 += __shfl_xor(rs1, 16); rs1 += __shfl_xor(rs1, 32);
        if (lgrp == 0) {
            s_rows[wr*NN + n0] = rs0;
            s_rows[wr*NN + n1] = rs1;
        }

        // epilogue: z = dn * acc + bias(fo), relu; f16x4 -> X; ssq; zpiv
        {
            const float dn[2] = { s_d[n0], s_d[n1] };
            float z[2][2][4];
            float ssc[2] = {0.f, 0.f};
            #pragma unroll
            for (int rt = 0; rt < 2; ++rt)
            #pragma unroll
            for (int ct = 0; ct < 2; ++ct) {
                f16x4 xv;
                #pragma unroll
                for (int q = 0; q < 4; ++q) {
                    float bq = rt ? ((const float*)&bv1)[q] : ((const float*)&bv0)[q];
                    float zv = fmaxf(fmaf(dn[ct], acc[rt][ct][q], bq), 0.f);
                    z[rt][ct][q] = zv;
                    ssc[ct] = fmaf(zv, zv, ssc[ct]);
                    xv[q] = (f16)zv;
                }
                *(f16x4*)(X + (wc*32 + ct*16 + lrow)*SP + wr*32 + rt*16 + lgrp*4) = xv;
            }
            ssc[0] += __shfl_xor(ssc[0], 16); ssc[0] += __shfl_xor(ssc[0], 32);
            ssc[1] += __shfl_xor(ssc[1], 16); ssc[1] += __shfl_xor(ssc[1], 32);
            if (lgrp == 0) {
                s_ssq[wr*NN + n0] = ssc[0];
                s_ssq[wr*NN + n1] = ssc[1];
            }
            // pivot-column lanes stash z[:,pn] (ternary ct select); z dies here
            if (pn < NN && wc == (pn >> 5) && lrow == (pn & 15)) {
                const int ctp = (pn >> 4) & 1;
                float4 v0, v1;
                #pragma unroll
                for (int q = 0; q < 4; ++q) {
                    ((float*)&v0)[q] = ctp ? z[0][1][q] : z[0][0][q];
                    ((float*)&v1)[q] = ctp ? z[1][1][q] : z[1][0][q];
                }
                *(float4*)(s_zpiv + wr*32 + lgrp*4)      = v0;
                *(float4*)(s_zpiv + wr*32 + 16 + lgrp*4) = v1;
            }
        }
        __syncthreads();

        // ========== P4: pd via X readback (own tile), then mm_a ==========
        if (pn < NN) {
            {
                const float4 zp0 = *(const float4*)(s_zpiv + wr*32 + lgrp*4);
                const float4 zp1 = *(const float4*)(s_zpiv + wr*32 + 16 + lgrp*4);
                float pd0 = 0.f, pd1 = 0.f;
                #pragma unroll
                for (int ct = 0; ct < 2; ++ct) {
                    f16x4 za = *(const f16x4*)(X + (wc*32 + ct*16 + lrow)*SP
                                                 + wr*32 + lgrp*4);
                    f16x4 zb = *(const f16x4*)(X + (wc*32 + ct*16 + lrow)*SP
                                                 + wr*32 + 16 + lgrp*4);
                    float s = 0.f;
                    #pragma unroll
                    for (int q = 0; q < 4; ++q) {
                        s = fmaf((float)za[q], ((const float*)&zp0)[q], s);
                        s = fmaf((float)zb[q], ((const float*)&zp1)[q], s);
                    }
                    if (ct == 0) pd0 = s; else pd1 = s;
                }
                pd0 += __shfl_xor(pd0, 16); pd0 += __shfl_xor(pd0, 32);
                pd1 += __shfl_xor(pd1, 16); pd1 += __shfl_xor(pd1, 32);
                if (lgrp == 0) {
                    s_pdt[wr*NN + n0] = pd0;
                    s_pdt[wr*NN + n1] = pd1;
                }
            }
            f16 dvh[2];
            #pragma unroll
            for (int rt = 0; rt < 2; ++rt) {
                const int row = wr*32 + rt*16 + lrow;
                float sq = s_ssq[row] + s_ssq[NN+row] + s_ssq[2*NN+row] + s_ssq[3*NN+row];
                float dv = (i == 0) ? 1.f : 1.f/(sqrtf(sq) + 1e-8f);
                dvh[rt] = (f16)fminf(dv, 60000.f);
            }
            run_mma(dvh[0], dvh[1]);
        }
        __syncthreads();

        // ========== P4c (wave 0): probs, out/patches, degrees, diag ======
        if (pn < NN && w == 0) {
            float sqp = s_ssq[pn] + s_ssq[NN+pn] + s_ssq[2*NN+pn] + s_ssq[3*NN+pn];
            float dp = (i == 0) ? 1.f : 1.f/(sqrtf(sqp) + 1e-8f);
            float pv[2];
            float sp = 0.f;
            #pragma unroll
            for (int h = 0; h < 2; ++h) {
                const int tt = lane + h*64;
                float p = 0.f;
                if (tt < pn) {
                    float r = s_pdt[tt] + s_pdt[NN+tt] + s_pdt[2*NN+tt] + s_pdt[3*NN+tt];
                    float sqj = s_ssq[tt] + s_ssq[NN+tt] + s_ssq[2*NN+tt] + s_ssq[3*NN+tt];
                    float dj = (i == 0) ? 1.f : 1.f/(sqrtf(sqj) + 1e-8f);
                    p = 1.f/(1.f + expf(-0.5f*r*dj*dp));
                    f16 pf = (f16)p;
                    outb[pn*NN + tt] = p;
                    outb[tt*NN + pn] = p;
                    Gn[pn*SP + tt] = pf;          // patch row pn
                    Gn[tt*SP + pn] = pf;          // patch col pn
                    sp += p;
                }
                pv[h] = p;
            }
            #pragma unroll
            for (int m2 = 1; m2 < 64; m2 <<= 1) sp += __shfl_xor(sp, m2);
            #pragma unroll
            for (int h = 0; h < 2; ++h) {
                const int tt = lane + h*64;
                float rsC = s_rows[tt] + s_rows[NN+tt] + s_rows[2*NN+tt] + s_rows[3*NN+tt];
                float dgC = s_diag[tt];                   // diag(C_i)_t
                float rsM = (tt < pn) ? (rsC + pv[h])
                          : ((tt == pn) ? (sp + dgC) : rsC);
                float dnew = 1.f/sqrtf(rsM + 1.f + 1e-8f);
                s_d[tt] = dnew;
                s_df16[tt] = (f16)dnew;
                s_diag[tt] = dnew*dnew*(dgC + 1.f);       // diag(C_{i+1})
                Gn[tt*SP + tt] = (f16)(dgC + 1.f);        // stored diag = dgC+1
            }
        }
        __syncthreads();
    }
}

extern "C" void kernel_launch(void* const* d_in, const int* in_sizes, int n_in,
                              void* d_out, int out_size, void* d_ws, size_t ws_size,
                              hipStream_t stream) {
    const float* x  = (const float*)d_in[0];
    const float* W  = (const float*)d_in[1];
    const float* bb = (const float*)d_in[2];
    float* out = (float*)d_out;

    const size_t shmem = (size_t)(4*NN*SP + NN)*sizeof(f16)
                       + (size_t)(3*NN + 4*NN + 4*NN + 4*NN)*sizeof(float);
    hipFuncSetAttribute((const void*)gcn_gen_kernel,
                        hipFuncAttributeMaxDynamicSharedMemorySize, (int)shmem);
    gcn_gen_kernel<<<8, 1024, shmem, stream>>>(x, W, bb, out);
}